// Round 13
// baseline (1004.479 us; speedup 1.0000x reference)
//
#include <hip/hip_runtime.h>
#include <math.h>

#define H 2048
#define IDIM 5632
#define NE 8
#define TT 2048            // tokens = 2*1024
#define LDW1 (2 * IDIM)    // 11264
#define NK1 (H / 64)       // 32
#define NK2 (IDIM / 64)    // 88

typedef __bf16 bf16x8 __attribute__((ext_vector_type(8)));
typedef float f32x4 __attribute__((ext_vector_type(4)));

__device__ __forceinline__ unsigned short f2bf(float f) {
    unsigned int u = __builtin_bit_cast(unsigned int, f);
    u += 0x7FFFu + ((u >> 16) & 1u);   // round-to-nearest-even
    return (unsigned short)(u >> 16);
}

// HW convert: compiler emits v_cvt_pk_bf16_f32 from paired casts (RTNE)
__device__ __forceinline__ unsigned int pk2(float a, float b) {
    __bf16 x = (__bf16)a, y = (__bf16)b;
    unsigned short lo = __builtin_bit_cast(unsigned short, x);
    unsigned short hi = __builtin_bit_cast(unsigned short, y);
    return (unsigned int)lo | ((unsigned int)hi << 16);
}

__device__ __forceinline__ void gload_lds16(const void* g, void* l) {
    __builtin_amdgcn_global_load_lds(
        (const __attribute__((address_space(1))) void*)g,
        (__attribute__((address_space(3))) void*)l, 16, 0, 0);
}

// ---------------- x (fp32) -> bf16 ----------------
__global__ void cvt_x_kernel(const float* __restrict__ x, unsigned short* __restrict__ xb) {
    int i = blockIdx.x * blockDim.x + threadIdx.x;
    float4 v = reinterpret_cast<const float4*>(x)[i];
    ushort4 o;
    o.x = f2bf(v.x); o.y = f2bf(v.y); o.z = f2bf(v.z); o.w = f2bf(v.w);
    reinterpret_cast<ushort4*>(xb)[i] = o;
}

// ---------------- router: fp64 logits, softmax, top-2, lists ----------------
__global__ void router_kernel(const float* __restrict__ x, const float* __restrict__ gw,
                              float* __restrict__ topw, int* __restrict__ cnt,
                              int* __restrict__ list) {
    int t = blockIdx.x;
    int lane = threadIdx.x;
    const float* xt = x + (size_t)t * H;
    double acc[NE];
#pragma unroll
    for (int e = 0; e < NE; ++e) acc[e] = 0.0;
    for (int h = lane; h < H; h += 64) {
        float xv = xt[h];
#pragma unroll
        for (int e = 0; e < NE; ++e) acc[e] += (double)xv * (double)gw[e * H + h];
    }
#pragma unroll
    for (int e = 0; e < NE; ++e) {
#pragma unroll
        for (int off = 32; off > 0; off >>= 1)
            acc[e] += __shfl_xor(acc[e], off, 64);
    }
    if (lane == 0) {
        double mx = acc[0];
#pragma unroll
        for (int e = 1; e < NE; ++e) mx = acc[e] > mx ? acc[e] : mx;
        double ex[NE], s = 0.0;
#pragma unroll
        for (int e = 0; e < NE; ++e) { ex[e] = exp(acc[e] - mx); s += ex[e]; }
        int e0 = 0; double b0 = ex[0];
#pragma unroll
        for (int e = 1; e < NE; ++e) if (ex[e] > b0) { b0 = ex[e]; e0 = e; }
        int e1 = -1; double b1 = -1.0;
#pragma unroll
        for (int e = 0; e < NE; ++e) if (e != e0 && ex[e] > b1) { b1 = ex[e]; e1 = e; }
        float p0 = (float)(b0 / s), p1 = (float)(b1 / s);
        float w0 = p0 / (p0 + p1), w1 = p1 / (p0 + p1);
        topw[t * 2 + 0] = w0;
        topw[t * 2 + 1] = w1;
        int pos0 = atomicAdd(&cnt[e0], 1); list[e0 * TT + pos0] = t * 2 + 0;
        int pos1 = atomicAdd(&cnt[e1], 1); list[e1 * TT + pos1] = t * 2 + 1;
    }
}

// ---------------- tile map (256-row tiles at [20..39]) ----------------
__global__ void setup_kernel(const int* __restrict__ cnt, int* __restrict__ tmap) {
    if (threadIdx.x == 0) {
        int a128 = 0, a256 = 0;
        tmap[0] = 0; tmap[20] = 0;
        for (int g = 0; g < 9; ++g) {
            int rows = (g == 0) ? TT : cnt[g - 1];
            tmap[10 + g] = rows;
            tmap[30 + g] = rows;
            a128 += (rows + 127) >> 7;
            a256 += (rows + 255) >> 8;
            tmap[g + 1] = a128;
            tmap[20 + g + 1] = a256;
        }
        tmap[19] = 0; tmap[39] = 0;
    }
}

// ============ GEMM1: 256 rows x 128 wcols, BK=64, producer/consumer wave split ========
// Waves 0-3: MFMA only (no VMEM in loop). Waves 4-7: all staging (A gload_lds,
// B fp32 dword loads + cvt_pk + conflict-free swizzled ds_write). One
// __syncthreads per K-tile: its vmcnt(0) drain lands only on producers.
__global__ __launch_bounds__(512)
void gemm1_kernel(const unsigned short* __restrict__ xb,
                  const float* __restrict__ base_gu,
                  const float* __restrict__ exp_gu,
                  const int* __restrict__ tmap,
                  const int* __restrict__ list,
                  unsigned short* __restrict__ actB,
                  unsigned short* __restrict__ actE) {
    __shared__ unsigned short lds_a[2][256 * 64];   // 32 KB each
    __shared__ unsigned short lds_b[2][128 * 64];   // 16 KB each
    __shared__ int s_arow[256];
    __shared__ int s_orow[256];
    __shared__ int sh[20];

    int tid = threadIdx.x;
    if (tid < 20) sh[tid] = tmap[20 + tid];
    __syncthreads();
    int bid = blockIdx.x;
    int virt = (bid & 7) * 352 + (bid >> 3);     // 2816 = 8*352; jcols contiguous per XCD
    int jcol = virt >> 5;                        // 0..87
    int rt = virt & 31;
    if (rt >= sh[9]) return;
    int g = 0;
    while (rt >= sh[g + 1]) ++g;
    int rows_g = sh[10 + g];
    int row0 = (rt - sh[g]) * 256;
    int n0a = jcol * 64;                         // act-col base (64 act cols = 128 wcols)

    if (tid < 256) {
        int r = row0 + tid;
        int arow = 0, orow = 0;
        if (r < rows_g) {
            if (g == 0) { arow = r; orow = r; }
            else { int e = list[(g - 1) * TT + r]; arow = e >> 1; orow = e; }
        }
        s_arow[tid] = arow;
        s_orow[tid] = orow;
    }
    __syncthreads();

    const float* W = (g == 0) ? base_gu : (exp_gu + (size_t)(g - 1) * H * LDW1);
    unsigned short* actPtr = (g == 0) ? actB : actE;

    int wave = tid >> 6, lane = tid & 63;
    bool producer = (wave >= 4);
    int ptid = tid & 255;                        // producer-local id

    // ---- producer state ----
    const unsigned short* asrc[8];
#pragma unroll
    for (int i = 0; i < 8; ++i) {
        int chunk = i * 256 + ptid;
        int sA = chunk >> 3, kc = chunk & 7;
        asrc[i] = xb + (size_t)s_arow[sA] * H + ((kc ^ (sA & 7)) << 3);
    }
    int dstoffA = (ptid >> 6) * 1024;            // wave-uniform; HW adds lane*16

    int cb = ptid & 63, ks = ptid >> 6;          // ks 0..3 -> k rows ks*16..+15
    int wcol0 = (((cb >> 5) & 1) ? IDIM : 0) + n0a + (cb & 31);
    const float* bp0 = W + (size_t)(ks * 16) * LDW1 + wcol0;
    const float* bp1 = bp0 + 32;                 // col cb+64 maps to wcol0+32
    int bwa[4];
    bwa[0] = cb * 128 + (((2 * ks) ^ (cb & 7)) << 4);
    bwa[1] = cb * 128 + (((2 * ks + 1) ^ (cb & 7)) << 4);
    bwa[2] = bwa[0] + 64 * 128;
    bwa[3] = bwa[1] + 64 * 128;

    auto stageTile = [&](int kt, int nb) {
#pragma unroll
        for (int i = 0; i < 8; ++i)
            gload_lds16(asrc[i] + kt * 64, (char*)lds_a[nb] + i * 4096 + dstoffA);
        float v0[16], v1[16];
#pragma unroll
        for (int r = 0; r < 16; ++r) {
            v0[r] = bp0[(size_t)(kt * 64 + r) * LDW1];
            v1[r] = bp1[(size_t)(kt * 64 + r) * LDW1];
        }
        char* pbw = (char*)lds_b[nb];
        uint4 pk;
        pk.x = pk2(v0[0], v0[1]);  pk.y = pk2(v0[2], v0[3]);
        pk.z = pk2(v0[4], v0[5]);  pk.w = pk2(v0[6], v0[7]);
        *reinterpret_cast<uint4*>(pbw + bwa[0]) = pk;
        pk.x = pk2(v0[8], v0[9]);  pk.y = pk2(v0[10], v0[11]);
        pk.z = pk2(v0[12], v0[13]); pk.w = pk2(v0[14], v0[15]);
        *reinterpret_cast<uint4*>(pbw + bwa[1]) = pk;
        pk.x = pk2(v1[0], v1[1]);  pk.y = pk2(v1[2], v1[3]);
        pk.z = pk2(v1[4], v1[5]);  pk.w = pk2(v1[6], v1[7]);
        *reinterpret_cast<uint4*>(pbw + bwa[2]) = pk;
        pk.x = pk2(v1[8], v1[9]);  pk.y = pk2(v1[10], v1[11]);
        pk.z = pk2(v1[12], v1[13]); pk.w = pk2(v1[14], v1[15]);
        *reinterpret_cast<uint4*>(pbw + bwa[3]) = pk;
    };

    // ---- consumer state: 4 waves = 2M x 2N; wave tile 128 x 64 ----
    int wr = (wave >> 1) & 1, wc = wave & 1;
    int arow0 = wr * 128 + (lane & 15);
    int bcol0 = wc * 64 + (lane & 15);
    int lxor = lane & 7;
    int kq = lane >> 4;

    f32x4 acc[8][4];
#pragma unroll
    for (int fm = 0; fm < 8; ++fm)
#pragma unroll
        for (int fn = 0; fn < 4; ++fn)
            acc[fm][fn] = (f32x4)(0.0f);

    auto compute = [&](int buf) {
        const char* pa = (const char*)lds_a[buf];
        const char* pb = (const char*)lds_b[buf];
#pragma unroll
        for (int kh = 0; kh < 2; ++kh) {
            int slot = ((kq + kh * 4) ^ lxor) << 4;
            bf16x8 bF[4], aF[8];
#pragma unroll
            for (int fn = 0; fn < 4; ++fn)
                bF[fn] = *reinterpret_cast<const bf16x8*>(pb + (bcol0 + fn * 16) * 128 + slot);
#pragma unroll
            for (int i = 0; i < 8; ++i)
                aF[i] = *reinterpret_cast<const bf16x8*>(pa + (arow0 + i * 16) * 128 + slot);
#pragma unroll
            for (int i = 0; i < 8; ++i)
#pragma unroll
                for (int fn = 0; fn < 4; ++fn)
                    acc[i][fn] = __builtin_amdgcn_mfma_f32_16x16x32_bf16(
                        aF[i], bF[fn], acc[i][fn], 0, 0, 0);
        }
    };

    if (producer) stageTile(0, 0);
    __syncthreads();
    for (int t = 0; t < NK1; ++t) {
        int buf = t & 1;
        if (!producer) compute(buf);
        else if (t + 1 < NK1) stageTile(t + 1, buf ^ 1);
        __syncthreads();
    }

    if (!producer) {
        int cq = lane >> 4, cr = lane & 15;
#pragma unroll
        for (int fm = 0; fm < 8; ++fm) {
#pragma unroll
            for (int r = 0; r < 4; ++r) {
                int rloc = wr * 128 + fm * 16 + cq * 4 + r;
                if (row0 + rloc < rows_g) {
                    size_t orow = (size_t)s_orow[rloc];
#pragma unroll
                    for (int fn = 0; fn < 2; ++fn) {
                        float gv = acc[fm][fn][r];
                        float uv = acc[fm][fn + 2][r];
                        float sv = gv / (1.0f + __expf(-gv));
                        int col = n0a + wc * 32 + fn * 16 + cr;
                        actPtr[orow * IDIM + col] = f2bf(sv * uv);
                    }
                }
            }
        }
    }
}

// ============ GEMM2: 256 rows x 128 cols, BK=64, same producer/consumer split =========
__global__ __launch_bounds__(512)
void gemm2_kernel(const unsigned short* __restrict__ actB,
                  const unsigned short* __restrict__ actE,
                  const float* __restrict__ base_dn,
                  const float* __restrict__ exp_dn,
                  const int* __restrict__ tmap,
                  const int* __restrict__ list,
                  float* __restrict__ outB,
                  float* __restrict__ yslot) {
    __shared__ unsigned short lds_a[2][256 * 64];
    __shared__ unsigned short lds_b[2][128 * 64];
    __shared__ int s_row[256];
    __shared__ int sh[20];

    int tid = threadIdx.x;
    if (tid < 20) sh[tid] = tmap[20 + tid];
    __syncthreads();
    int bid = blockIdx.x;
    int virt = (bid & 7) * 64 + (bid >> 3);      // 512 = 8*64; 2 jcols per XCD
    int jcol = virt >> 5;                        // 0..15
    int rt = virt & 31;
    if (rt >= sh[9]) return;
    int g = 0;
    while (rt >= sh[g + 1]) ++g;
    int rows_g = sh[10 + g];
    int row0 = (rt - sh[g]) * 256;
    int n0 = jcol * 128;

    if (tid < 256) {
        int r = row0 + tid;
        int rowi = 0;
        if (r < rows_g) rowi = (g == 0) ? r : list[(g - 1) * TT + r];
        s_row[tid] = rowi;
    }
    __syncthreads();

    const unsigned short* abase = (g == 0) ? actB : actE;
    const float* W = (g == 0) ? base_dn : (exp_dn + (size_t)(g - 1) * IDIM * H);
    float* obase = (g == 0) ? outB : yslot;

    int wave = tid >> 6, lane = tid & 63;
    bool producer = (wave >= 4);
    int ptid = tid & 255;

    const unsigned short* asrc[8];
#pragma unroll
    for (int i = 0; i < 8; ++i) {
        int chunk = i * 256 + ptid;
        int sA = chunk >> 3, kc = chunk & 7;
        asrc[i] = abase + (size_t)s_row[sA] * IDIM + ((kc ^ (sA & 7)) << 3);
    }
    int dstoffA = (ptid >> 6) * 1024;

    int cb = ptid & 63, ks = ptid >> 6;
    const float* bp0 = W + (size_t)(ks * 16) * H + n0 + cb;
    const float* bp1 = bp0 + 64;
    int bwa[4];
    bwa[0] = cb * 128 + (((2 * ks) ^ (cb & 7)) << 4);
    bwa[1] = cb * 128 + (((2 * ks + 1) ^ (cb & 7)) << 4);
    bwa[2] = bwa[0] + 64 * 128;
    bwa[3] = bwa[1] + 64 * 128;

    auto stageTile = [&](int kt, int nb) {
#pragma unroll
        for (int i = 0; i < 8; ++i)
            gload_lds16(asrc[i] + kt * 64, (char*)lds_a[nb] + i * 4096 + dstoffA);
        float v0[16], v1[16];
#pragma unroll
        for (int r = 0; r < 16; ++r) {
            v0[r] = bp0[(size_t)(kt * 64 + r) * H];
            v1[r] = bp1[(size_t)(kt * 64 + r) * H];
        }
        char* pbw = (char*)lds_b[nb];
        uint4 pk;
        pk.x = pk2(v0[0], v0[1]);  pk.y = pk2(v0[2], v0[3]);
        pk.z = pk2(v0[4], v0[5]);  pk.w = pk2(v0[6], v0[7]);
        *reinterpret_cast<uint4*>(pbw + bwa[0]) = pk;
        pk.x = pk2(v0[8], v0[9]);  pk.y = pk2(v0[10], v0[11]);
        pk.z = pk2(v0[12], v0[13]); pk.w = pk2(v0[14], v0[15]);
        *reinterpret_cast<uint4*>(pbw + bwa[1]) = pk;
        pk.x = pk2(v1[0], v1[1]);  pk.y = pk2(v1[2], v1[3]);
        pk.z = pk2(v1[4], v1[5]);  pk.w = pk2(v1[6], v1[7]);
        *reinterpret_cast<uint4*>(pbw + bwa[2]) = pk;
        pk.x = pk2(v1[8], v1[9]);  pk.y = pk2(v1[10], v1[11]);
        pk.z = pk2(v1[12], v1[13]); pk.w = pk2(v1[14], v1[15]);
        *reinterpret_cast<uint4*>(pbw + bwa[3]) = pk;
    };

    int wr = (wave >> 1) & 1, wc = wave & 1;
    int arow0 = wr * 128 + (lane & 15);
    int bcol0 = wc * 64 + (lane & 15);
    int lxor = lane & 7;
    int kq = lane >> 4;

    f32x4 acc[8][4];
#pragma unroll
    for (int fm = 0; fm < 8; ++fm)
#pragma unroll
        for (int fn = 0; fn < 4; ++fn)
            acc[fm][fn] = (f32x4)(0.0f);

    auto compute = [&](int buf) {
        const char* pa = (const char*)lds_a[buf];
        const char* pb = (const char*)lds_b[buf];
#pragma unroll
        for (int kh = 0; kh < 2; ++kh) {
            int slot = ((kq + kh * 4) ^ lxor) << 4;
            bf16x8 bF[4], aF[8];
#pragma unroll
            for (int fn = 0; fn < 4; ++fn)
                bF[fn] = *reinterpret_cast<const bf16x8*>(pb + (bcol0 + fn * 16) * 128 + slot);
#pragma unroll
            for (int i = 0; i < 8; ++i)
                aF[i] = *reinterpret_cast<const bf16x8*>(pa + (arow0 + i * 16) * 128 + slot);
#pragma unroll
            for (int i = 0; i < 8; ++i)
#pragma unroll
                for (int fn = 0; fn < 4; ++fn)
                    acc[i][fn] = __builtin_amdgcn_mfma_f32_16x16x32_bf16(
                        aF[i], bF[fn], acc[i][fn], 0, 0, 0);
        }
    };

    if (producer) stageTile(0, 0);
    __syncthreads();
    for (int t = 0; t < NK2; ++t) {
        int buf = t & 1;
        if (!producer) compute(buf);
        else if (t + 1 < NK2) stageTile(t + 1, buf ^ 1);
        __syncthreads();
    }

    if (!producer) {
        int cq = lane >> 4, cr = lane & 15;
#pragma unroll
        for (int fm = 0; fm < 8; ++fm) {
#pragma unroll
            for (int r = 0; r < 4; ++r) {
                int rloc = wr * 128 + fm * 16 + cq * 4 + r;
                if (row0 + rloc < rows_g) {
                    size_t orow = (size_t)s_row[rloc];
#pragma unroll
                    for (int fn = 0; fn < 4; ++fn) {
                        int col = n0 + wc * 64 + fn * 16 + cr;
                        obase[orow * H + col] = acc[fm][fn][r];
                    }
                }
            }
        }
    }
}

// ---------------- combine: out += w0*y0 + w1*y1 ----------------
__global__ void combine_kernel(float* __restrict__ out, const float* __restrict__ yslot,
                               const float* __restrict__ topw) {
    int i = blockIdx.x * blockDim.x + threadIdx.x;
    int t = i >> 9;
    int c = (i & 511) << 2;
    float w0 = topw[t * 2], w1 = topw[t * 2 + 1];
    float4 y0 = *reinterpret_cast<const float4*>(yslot + ((size_t)(2 * t) * H + c));
    float4 y1 = *reinterpret_cast<const float4*>(yslot + ((size_t)(2 * t + 1) * H + c));
    float4* po = reinterpret_cast<float4*>(out + ((size_t)t * H + c));
    float4 o = *po;
    o.x += w0 * y0.x + w1 * y1.x;
    o.y += w0 * y0.y + w1 * y1.y;
    o.z += w0 * y0.z + w1 * y1.z;
    o.w += w0 * y0.w + w1 * y1.w;
    *po = o;
}

extern "C" void kernel_launch(void* const* d_in, const int* in_sizes, int n_in,
                              void* d_out, int out_size, void* d_ws, size_t ws_size,
                              hipStream_t stream) {
    const float* x   = (const float*)d_in[0];
    const float* gw  = (const float*)d_in[1];
    const float* bgu = (const float*)d_in[2];
    const float* bdn = (const float*)d_in[3];
    const float* egu = (const float*)d_in[4];
    const float* edn = (const float*)d_in[5];
    float* out = (float*)d_out;
    char* ws = (char*)d_ws;

    unsigned short* xb   = (unsigned short*)(ws + 0);          //  8,388,608 B
    unsigned short* actB = (unsigned short*)(ws + 8388608);    // 23,068,672 B
    unsigned short* actE = (unsigned short*)(ws + 31457280);   // 46,137,344 B
    float* yslot         = (float*)(ws + 77594624);            // 33,554,432 B
    float* topw          = (float*)(ws + 111149056);
    int* cnt             = (int*)(ws + 111165440);
    int* list            = (int*)(ws + 111165696);
    int* tmap            = (int*)(ws + 111231232);

    hipMemsetAsync(cnt, 0, NE * sizeof(int), stream);
    cvt_x_kernel<<<4096, 256, 0, stream>>>(x, xb);
    router_kernel<<<TT, 64, 0, stream>>>(x, gw, topw, cnt, list);
    setup_kernel<<<1, 64, 0, stream>>>(cnt, tmap);
    // gemm1: 88 col-strips x up-to-32 row-tiles, XCD-pinned
    gemm1_kernel<<<2816, 512, 0, stream>>>(xb, bgu, egu, tmap, list, actB, actE);
    // gemm2: 16 col-strips x up-to-32 row-tiles
    gemm2_kernel<<<512, 512, 0, stream>>>(actB, actE, bdn, edn, tmap, list, out, yslot);
    combine_kernel<<<4096, 256, 0, stream>>>(out, yslot, topw);
}